// Round 1
// baseline (2145.282 us; speedup 1.0000x reference)
//
#include <hip/hip_runtime.h>

// ---------- types ----------
typedef __bf16 bf16x8 __attribute__((ext_vector_type(8)));
typedef float f32x4 __attribute__((ext_vector_type(4)));

#define EPS 1e-5f

__device__ __forceinline__ unsigned short f2bu(float f) {
  union { float f; unsigned u; } x; x.f = f;
  unsigned r = x.u + 0x7fffu + ((x.u >> 16) & 1u);  // RNE
  return (unsigned short)(r >> 16);
}
__device__ __forceinline__ float bu2f(unsigned short u) {
  union { unsigned u; float f; } x; x.u = ((unsigned)u) << 16;
  return x.f;
}

// ---------- generic f32 -> bf16 convert ----------
__global__ __launch_bounds__(256) void k_f2b(const float* __restrict__ in,
                                             unsigned short* __restrict__ out, int n) {
  int i = blockIdx.x * 256 + threadIdx.x;
  if (i < n) out[i] = f2bu(in[i]);
}

// ---------- conv weight repack (CO,CI,3,3) f32 -> (CO,9,CI) bf16 ----------
template <int CI>
__global__ __launch_bounds__(256) void k_repack(const float* __restrict__ w,
                                                unsigned short* __restrict__ out, int n) {
  int id = blockIdx.x * 256 + threadIdx.x;
  if (id >= n) return;
  int ci = id % CI;
  int tap = (id / CI) % 9;
  int co = id / (9 * CI);
  out[id] = f2bu(w[(co * CI + ci) * 9 + tap]);
}

// ---------- fused conv1(3x3,s2,p1) + BN + ReLU + maxpool(3,2,1) -> NHWC bf16 ----------
__global__ __launch_bounds__(256) void k_conv1(
    const float* __restrict__ x, const float* __restrict__ w,
    const float* __restrict__ cb, const float* __restrict__ g,
    const float* __restrict__ bb, const float* __restrict__ bm_,
    const float* __restrict__ bv, unsigned short* __restrict__ out) {
  int id = blockIdx.x * 256 + threadIdx.x;  // ((b*56+py)*56+px)*64 + c
  int c = id & 63;
  int t = id >> 6;
  int px = t % 56; t /= 56;
  int py = t % 56;
  int b = t / 56;
  float alpha = g[c] * rsqrtf(bv[c] + EPS);
  float beta = (cb[c] - bm_[c]) * alpha + bb[c];
  float wr[27];
#pragma unroll
  for (int i = 0; i < 27; ++i) wr[i] = w[c * 27 + i];
  const float* xb = x + (size_t)b * 3 * 224 * 224;
  float best = -3.4e38f;
#pragma unroll
  for (int wy = -1; wy <= 1; ++wy) {
    int oy = py * 2 + wy;
    if ((unsigned)oy >= 112u) continue;
#pragma unroll
    for (int wx = -1; wx <= 1; ++wx) {
      int ox = px * 2 + wx;
      if ((unsigned)ox >= 112u) continue;
      float acc = 0.f;
#pragma unroll
      for (int ky = 0; ky < 3; ++ky) {
        int iy = oy * 2 - 1 + ky;
        if ((unsigned)iy >= 224u) continue;
#pragma unroll
        for (int kx = 0; kx < 3; ++kx) {
          int ix = ox * 2 - 1 + kx;
          if ((unsigned)ix >= 224u) continue;
#pragma unroll
          for (int ci = 0; ci < 3; ++ci)
            acc = fmaf(xb[(ci * 224 + iy) * 224 + ix], wr[(ci * 3 + ky) * 3 + kx], acc);
        }
      }
      float v = fmaxf(acc * alpha + beta, 0.f);
      best = fmaxf(best, v);
    }
  }
  out[id] = f2bu(best);
}

// ---------- implicit-GEMM 3x3 s1 p1 conv, NHWC bf16 in/out, BN+ReLU epilogue ----------
template <int H, int Wd, int CI, int CO>
__global__ __launch_bounds__(256) void k_convgemm(
    const unsigned short* __restrict__ In, const unsigned short* __restrict__ Wt,
    const float* __restrict__ cb, const float* __restrict__ g,
    const float* __restrict__ bb, const float* __restrict__ bm_,
    const float* __restrict__ bv, unsigned short* __restrict__ Out) {
  constexpr int K = 9 * CI;
  constexpr int NTN = CO / 64;
  int bm = blockIdx.x / NTN, bn = blockIdx.x - bm * NTN;
  int lane = threadIdx.x & 63, wid = threadIdx.x >> 6;
  int wr = wid >> 1, wc = wid & 1;
  int r0 = bm * 64 + wr * 32 + (lane & 15);
  int r1 = r0 + 16;
  int c0 = bn * 64 + wc * 32 + (lane & 15);
  int koff = (lane >> 4) << 3;
  int ox0 = r0 % Wd; int t0 = r0 / Wd; int oy0 = t0 % H; int b0 = t0 / H;
  int ox1 = r1 % Wd; int t1 = r1 / Wd; int oy1 = t1 % H; int b1 = t1 / H;
  const unsigned short* pb0 = Wt + (size_t)c0 * K + koff;
  const unsigned short* pb1 = Wt + (size_t)(c0 + 16) * K + koff;
  f32x4 acc[2][2] = {};
  for (int k0 = 0; k0 < K; k0 += 32) {
    int k = k0 + koff;
    int tap = k / CI;
    int ci = k - tap * CI;
    int ky = tap / 3, kx = tap - ky * 3;
    int iy0 = oy0 + ky - 1, ix0 = ox0 + kx - 1;
    int iy1 = oy1 + ky - 1, ix1 = ox1 + kx - 1;
    bf16x8 a0 = {};
    bf16x8 a1 = {};
    if ((unsigned)iy0 < (unsigned)H && (unsigned)ix0 < (unsigned)Wd)
      a0 = *(const bf16x8*)(In + ((size_t)((b0 * H + iy0) * Wd + ix0)) * CI + ci);
    if ((unsigned)iy1 < (unsigned)H && (unsigned)ix1 < (unsigned)Wd)
      a1 = *(const bf16x8*)(In + ((size_t)((b1 * H + iy1) * Wd + ix1)) * CI + ci);
    bf16x8 w0 = *(const bf16x8*)(pb0 + k0);
    bf16x8 w1 = *(const bf16x8*)(pb1 + k0);
    acc[0][0] = __builtin_amdgcn_mfma_f32_16x16x32_bf16(a0, w0, acc[0][0], 0, 0, 0);
    acc[0][1] = __builtin_amdgcn_mfma_f32_16x16x32_bf16(a0, w1, acc[0][1], 0, 0, 0);
    acc[1][0] = __builtin_amdgcn_mfma_f32_16x16x32_bf16(a1, w0, acc[1][0], 0, 0, 0);
    acc[1][1] = __builtin_amdgcn_mfma_f32_16x16x32_bf16(a1, w1, acc[1][1], 0, 0, 0);
  }
  int rr = (lane >> 4) * 4, rc = lane & 15;
#pragma unroll
  for (int tj = 0; tj < 2; ++tj) {
    int col = bn * 64 + wc * 32 + tj * 16 + rc;
    float alpha = g[col] * rsqrtf(bv[col] + EPS);
    float beta = (cb[col] - bm_[col]) * alpha + bb[col];
#pragma unroll
    for (int ti = 0; ti < 2; ++ti) {
      int row = bm * 64 + wr * 32 + ti * 16 + rr;
#pragma unroll
      for (int r = 0; r < 4; ++r) {
        float v = fmaxf(acc[ti][tj][r] * alpha + beta, 0.f);
        Out[(size_t)(row + r) * CO + col] = f2bu(v);
      }
    }
  }
}

// ---------- NHWC 2x2/2 maxpool, bf16 in, bf16 or f32 out ----------
template <int H, int Wd, int C, bool OUTF>
__global__ __launch_bounds__(256) void k_pool(const unsigned short* __restrict__ in,
                                              void* __restrict__ outv) {
  constexpr int OH = H / 2, OW = Wd / 2;
  int id = blockIdx.x * 256 + threadIdx.x;  // 32*OH*OW*C exact
  int c = id % C;
  int t = id / C;
  int px = t % OW; t /= OW;
  int py = t % OH;
  int b = t / OH;
  const unsigned short* p = in + (((size_t)(b * H + py * 2) * Wd) + px * 2) * C + c;
  float m0 = bu2f(p[0]), m1 = bu2f(p[C]);
  float m2 = bu2f(p[(size_t)Wd * C]), m3 = bu2f(p[(size_t)Wd * C + C]);
  float m = fmaxf(fmaxf(m0, m1), fmaxf(m2, m3));
  if (OUTF) ((float*)outv)[id] = m;
  else ((unsigned short*)outv)[id] = f2bu(m);
}

// ---------- LayerNorm over 256, f32 in -> bf16 out ----------
__global__ __launch_bounds__(256) void k_ln(const float* __restrict__ h,
                                            const float* __restrict__ g,
                                            const float* __restrict__ b2,
                                            unsigned short* __restrict__ out) {
  int lane = threadIdx.x & 63, wid = threadIdx.x >> 6;
  int t = blockIdx.x * 4 + wid;
  float4 v = *(const float4*)(h + (size_t)t * 256 + lane * 4);
  float s = v.x + v.y + v.z + v.w;
  float q = v.x * v.x + v.y * v.y + v.z * v.z + v.w * v.w;
#pragma unroll
  for (int off = 32; off; off >>= 1) {
    s += __shfl_xor(s, off);
    q += __shfl_xor(q, off);
  }
  float mu = s * (1.f / 256.f);
  float var = q * (1.f / 256.f) - mu * mu;
  float rs = rsqrtf(var + EPS);
  float4 gg = *(const float4*)(g + lane * 4);
  float4 bb = *(const float4*)(b2 + lane * 4);
  ushort4 o;
  o.x = f2bu((v.x - mu) * rs * gg.x + bb.x);
  o.y = f2bu((v.y - mu) * rs * gg.y + bb.y);
  o.z = f2bu((v.z - mu) * rs * gg.z + bb.z);
  o.w = f2bu((v.w - mu) * rs * gg.w + bb.w);
  *(ushort4*)(out + (size_t)t * 256 + lane * 4) = o;
}

// ---------- generic bf16 GEMM: C[M,N] = A[M,K] @ W[N,K]^T (optional += C) ----------
template <bool ADD_RES>
__global__ __launch_bounds__(256) void k_gemm(const unsigned short* __restrict__ A,
                                              const unsigned short* __restrict__ W,
                                              float* __restrict__ C, int M, int N,
                                              int K, int ntn) {
  int bm = blockIdx.x / ntn, bn = blockIdx.x - bm * ntn;
  int lane = threadIdx.x & 63, wid = threadIdx.x >> 6;
  int wr = wid >> 1, wc = wid & 1;
  int r0 = bm * 64 + wr * 32 + (lane & 15);
  int c0 = bn * 64 + wc * 32 + (lane & 15);
  int koff = (lane >> 4) << 3;
  int cc0 = (c0 < N) ? c0 : (N - 1);
  int cc1 = (c0 + 16 < N) ? (c0 + 16) : (N - 1);
  const unsigned short* pa0 = A + (size_t)r0 * K + koff;
  const unsigned short* pa1 = A + (size_t)(r0 + 16) * K + koff;
  const unsigned short* pb0 = W + (size_t)cc0 * K + koff;
  const unsigned short* pb1 = W + (size_t)cc1 * K + koff;
  f32x4 acc[2][2] = {};
  for (int k0 = 0; k0 < K; k0 += 32) {
    bf16x8 a0 = *(const bf16x8*)(pa0 + k0);
    bf16x8 a1 = *(const bf16x8*)(pa1 + k0);
    bf16x8 b0 = *(const bf16x8*)(pb0 + k0);
    bf16x8 b1 = *(const bf16x8*)(pb1 + k0);
    acc[0][0] = __builtin_amdgcn_mfma_f32_16x16x32_bf16(a0, b0, acc[0][0], 0, 0, 0);
    acc[0][1] = __builtin_amdgcn_mfma_f32_16x16x32_bf16(a0, b1, acc[0][1], 0, 0, 0);
    acc[1][0] = __builtin_amdgcn_mfma_f32_16x16x32_bf16(a1, b0, acc[1][0], 0, 0, 0);
    acc[1][1] = __builtin_amdgcn_mfma_f32_16x16x32_bf16(a1, b1, acc[1][1], 0, 0, 0);
  }
  int rr = (lane >> 4) * 4, rc = lane & 15;
#pragma unroll
  for (int ti = 0; ti < 2; ++ti)
#pragma unroll
    for (int tj = 0; tj < 2; ++tj) {
      int col = bn * 64 + wc * 32 + tj * 16 + rc;
      if (col >= N) continue;
      int row = bm * 64 + wr * 32 + ti * 16 + rr;
#pragma unroll
      for (int r = 0; r < 4; ++r) {
        float v = acc[ti][tj][r];
        if (ADD_RES) v += C[(size_t)(row + r) * N + col];
        C[(size_t)(row + r) * N + col] = v;
      }
    }
}

// ---------- depthwise causal conv (DC=4) + silu; writes f32 + bf16 ----------
__global__ __launch_bounds__(256) void k_dwconv(const float* __restrict__ xz,
                                                const float* __restrict__ cw,
                                                const float* __restrict__ cb,
                                                float* __restrict__ xc,
                                                unsigned short* __restrict__ xcb) {
  int id = blockIdx.x * 256 + threadIdx.x;  // 6272*512
  int d = id & 511;
  int bl = id >> 9;
  int l = bl % 196;
  int b = bl / 196;
  const float* xi = xz + (size_t)(b * 196) * 1024 + d;
  float4 c4 = *(const float4*)(cw + d * 4);
  float acc = cb[d];
  if (l >= 3) acc = fmaf(xi[(size_t)(l - 3) * 1024], c4.x, acc);
  if (l >= 2) acc = fmaf(xi[(size_t)(l - 2) * 1024], c4.y, acc);
  if (l >= 1) acc = fmaf(xi[(size_t)(l - 1) * 1024], c4.z, acc);
  acc = fmaf(xi[(size_t)l * 1024], c4.w, acc);
  float s = acc / (1.f + __expf(-acc));
  xc[id] = s;
  xcb[id] = f2bu(s);
}

// ---------- dt = softplus(dbl[:, :16] @ w_dt^T + b_dt) ----------
__global__ __launch_bounds__(256) void k_dt(const float* __restrict__ dbl,
                                            const float* __restrict__ wdt,
                                            const float* __restrict__ bdt,
                                            float* __restrict__ dt) {
  int id = blockIdx.x * 256 + threadIdx.x;  // 6272*512
  int d = id & 511;
  int bl = id >> 9;
  const float4* a = (const float4*)(dbl + (size_t)bl * 144);
  const float4* w = (const float4*)(wdt + d * 16);
  float acc = bdt[d];
#pragma unroll
  for (int i = 0; i < 4; ++i) {
    float4 av = a[i], wv = w[i];
    acc += av.x * wv.x + av.y * wv.y + av.z * wv.z + av.w * wv.w;
  }
  dt[id] = fmaxf(acc, 0.f) + log1pf(__expf(-fabsf(acc)));
}

// ---------- selective scan: wave per (b,d), lane = state s ----------
__global__ __launch_bounds__(256) void k_scan(
    const float* __restrict__ dtb, const float* __restrict__ xc,
    const float* __restrict__ dbl, const float* __restrict__ xz,
    const float* __restrict__ a_log, const float* __restrict__ d_skip,
    unsigned short* __restrict__ y) {
  __shared__ float lds[4][584];
  int lane = threadIdx.x & 63, wid = threadIdx.x >> 6;
  int wgid = blockIdx.x * 4 + wid;  // 0..16383
  int b = wgid >> 9, d = wgid & 511;
  float A = -__expf(a_log[d * 64 + lane]);
  float dsk = d_skip[d];
  const float* dt_p = dtb + (size_t)(b * 196) * 512 + d;
  const float* xc_p = xc + (size_t)(b * 196) * 512 + d;
  const float* z_p = xz + (size_t)(b * 196) * 1024 + 512 + d;
  const float* bc_p = dbl + (size_t)(b * 196) * 144 + 16 + lane;
  unsigned short* y_p = y + (size_t)(b * 196) * 512 + d;
  float* L = lds[wid];
  float h = 0.f;
  int g = lane >> 3, j = lane & 7;
  for (int l0 = 0; l0 < 196; l0 += 8) {
    float p[8];
#pragma unroll
    for (int li = 0; li < 8; ++li) {
      int l = l0 + li;
      bool ok = (l < 196);
      float dtv = ok ? dt_p[(size_t)l * 512] : 0.f;
      float xv = ok ? xc_p[(size_t)l * 512] : 0.f;
      float Bv = ok ? bc_p[(size_t)l * 144] : 0.f;
      float Cv = ok ? bc_p[(size_t)l * 144 + 64] : 0.f;
      float dA = __expf(dtv * A);
      h = fmaf(dA, h, (dtv * xv) * Bv);
      p[li] = h * Cv;
    }
#pragma unroll
    for (int li = 0; li < 8; ++li) L[lane * 9 + li] = p[li];
    __builtin_amdgcn_wave_barrier();
    float s = 0.f;
#pragma unroll
    for (int k = 0; k < 8; ++k) s += L[(j * 8 + k) * 9 + g];
    __builtin_amdgcn_wave_barrier();
    s += __shfl_xor(s, 1);
    s += __shfl_xor(s, 2);
    s += __shfl_xor(s, 4);
    int l = l0 + g;
    if (j == 0 && l < 196) {
      float xv = xc_p[(size_t)l * 512];
      float zv = z_p[(size_t)l * 1024];
      float sig = 1.f / (1.f + __expf(-zv));
      y_p[(size_t)l * 512] = f2bu((s + dsk * xv) * (zv * sig));
    }
  }
}

// ---------- head ----------
__global__ __launch_bounds__(256) void k_mean(const float* __restrict__ h,
                                              float* __restrict__ pooled) {
  int b = blockIdx.x, e = threadIdx.x;
  float s = 0.f;
  for (int l = 0; l < 196; ++l) s += h[(size_t)(b * 196 + l) * 256 + e];
  pooled[b * 256 + e] = s * (1.f / 196.f);
}

__global__ __launch_bounds__(320) void k_fc(const float* __restrict__ pooled,
                                            const float* __restrict__ fw,
                                            const float* __restrict__ fb,
                                            float* __restrict__ out) {
  int t = threadIdx.x;
  if (t >= 320) return;
  int b = t / 10, n = t - b * 10;
  float s = fb[n];
  for (int e = 0; e < 256; ++e) s += pooled[b * 256 + e] * fw[n * 256 + e];
  out[t] = s;
}

// ---------- launcher ----------
static inline unsigned cdiv(unsigned a, unsigned b) { return (a + b - 1) / b; }

extern "C" void kernel_launch(void* const* d_in, const int* in_sizes, int n_in,
                              void* d_out, int out_size, void* d_ws, size_t ws_size,
                              hipStream_t stream) {
  const float* x = (const float*)d_in[0];
  const float* c1w = (const float*)d_in[1]; const float* c1b = (const float*)d_in[2];
  const float* b1g = (const float*)d_in[3]; const float* b1b = (const float*)d_in[4];
  const float* b1m = (const float*)d_in[5]; const float* b1v = (const float*)d_in[6];
  const float* c2w = (const float*)d_in[7]; const float* c2b = (const float*)d_in[8];
  const float* b2g = (const float*)d_in[9]; const float* b2b = (const float*)d_in[10];
  const float* b2m = (const float*)d_in[11]; const float* b2v = (const float*)d_in[12];
  const float* c3w = (const float*)d_in[13]; const float* c3b = (const float*)d_in[14];
  const float* b3g = (const float*)d_in[15]; const float* b3b = (const float*)d_in[16];
  const float* b3m = (const float*)d_in[17]; const float* b3v = (const float*)d_in[18];
  const float* ln_g = (const float*)d_in[19]; const float* ln_b = (const float*)d_in[20];
  const float* w_in = (const float*)d_in[21];
  const float* cw = (const float*)d_in[22]; const float* cbv = (const float*)d_in[23];
  const float* w_x = (const float*)d_in[24];
  const float* w_dt = (const float*)d_in[25]; const float* b_dt = (const float*)d_in[26];
  const float* a_log = (const float*)d_in[27]; const float* d_skip = (const float*)d_in[28];
  const float* w_out = (const float*)d_in[29];
  const float* fc_w = (const float*)d_in[30]; const float* fc_b = (const float*)d_in[31];

  char* ws = (char*)d_ws;
  size_t off = 0;
  auto take = [&](size_t bytes) { size_t o = off; off += bytes; return o; };
  // scratch region S: stem buffers (phase 1) union mamba buffers (phase 2)
  size_t S = take(67837952);
  unsigned short* t1 = (unsigned short*)(ws + S + 0);
  unsigned short* t2 = (unsigned short*)(ws + S + 12845056);
  unsigned short* t3 = (unsigned short*)(ws + S + 38535168);
  unsigned short* t4 = (unsigned short*)(ws + S + 44957696);
  float* xz = (float*)(ws + S + 0);
  float* xc = (float*)(ws + S + 25690112);
  unsigned short* xcb = (unsigned short*)(ws + S + 38535168);
  float* dbl = (float*)(ws + S + 44957696);
  float* dtb = (float*)(ws + S + 48570368);
  unsigned short* ybf = (unsigned short*)(ws + S + 61415424);
  float* h = (float*)(ws + take(6422528));
  unsigned short* hbf = (unsigned short*)(ws + take(3211264));
  unsigned short* w_in_bf = (unsigned short*)(ws + take(3145728));
  unsigned short* w_x_bf = (unsigned short*)(ws + take(884736));
  unsigned short* w_out_bf = (unsigned short*)(ws + take(1572864));
  unsigned short* w2p = (unsigned short*)(ws + take(147456));
  unsigned short* w3p = (unsigned short*)(ws + take(589824));
  float* pooled = (float*)(ws + take(32768));
  (void)ws_size; (void)in_sizes; (void)n_in; (void)out_size;

  // weight conversion / repack
  k_f2b<<<cdiv(1572864, 256), 256, 0, stream>>>(w_in, w_in_bf, 1572864);
  k_f2b<<<cdiv(442368, 256), 256, 0, stream>>>(w_x, w_x_bf, 442368);
  k_f2b<<<cdiv(786432, 256), 256, 0, stream>>>(w_out, w_out_bf, 786432);
  k_repack<64><<<cdiv(73728, 256), 256, 0, stream>>>(c2w, w2p, 73728);
  k_repack<128><<<cdiv(294912, 256), 256, 0, stream>>>(c3w, w3p, 294912);

  // stem
  k_conv1<<<25088, 256, 0, stream>>>(x, c1w, c1b, b1g, b1b, b1m, b1v, t1);
  k_convgemm<56, 56, 64, 128><<<1568 * 2, 256, 0, stream>>>(t1, w2p, c2b, b2g, b2b, b2m, b2v, t2);
  k_pool<56, 56, 128, false><<<12544, 256, 0, stream>>>(t2, t3);
  k_convgemm<28, 28, 128, 256><<<392 * 4, 256, 0, stream>>>(t3, w3p, c3b, b3g, b3b, b3m, b3v, t4);
  k_pool<28, 28, 256, true><<<6272, 256, 0, stream>>>(t4, h);

  // mamba blocks
  for (int blk = 0; blk < 6; ++blk) {
    k_ln<<<1568, 256, 0, stream>>>(h, ln_g + blk * 256, ln_b + blk * 256, hbf);
    k_gemm<false><<<98 * 16, 256, 0, stream>>>(hbf, w_in_bf + (size_t)blk * 1024 * 256, xz,
                                               6272, 1024, 256, 16);
    k_dwconv<<<12544, 256, 0, stream>>>(xz, cw + blk * 512 * 4, cbv + blk * 512, xc, xcb);
    k_gemm<false><<<98 * 3, 256, 0, stream>>>(xcb, w_x_bf + (size_t)blk * 144 * 512, dbl,
                                              6272, 144, 512, 3);
    k_dt<<<12544, 256, 0, stream>>>(dbl, w_dt + blk * 512 * 16, b_dt + blk * 512, dtb);
    k_scan<<<4096, 256, 0, stream>>>(dtb, xc, dbl, xz, a_log + blk * 512 * 64,
                                     d_skip + blk * 512, ybf);
    k_gemm<true><<<98 * 4, 256, 0, stream>>>(ybf, w_out_bf + (size_t)blk * 256 * 512, h,
                                             6272, 256, 512, 4);
  }

  // head
  k_mean<<<32, 256, 0, stream>>>(h, pooled);
  k_fc<<<1, 320, 0, stream>>>(pooled, fc_w, fc_b, (float*)d_out);
}